// Round 1
// baseline (16306.120 us; speedup 1.0000x reference)
//
#include <hip/hip_runtime.h>

// MPNN encoder, MI355X. f32 throughout (reference is f32; no fp32 MFMA on CDNA4,
// so edge MLP runs on VALU with scalar-loaded weights).
//
// Key derivations from the reference:
//  - edge_feat / GRU_e / W3-message reuse for 'b' are DEAD w.r.t. the output -> skipped.
//  - layer1 pre-activation factorized: h1 = relu(u[s] + v[d] + W1p*dpos + b1),
//    u = node@W1s.T, v = node@W1d.T computed per-node once per iteration.
//  - segment_sum(m, esym[0]) -> f32 atomics into acc[node][32].

#define NN      50000
#define NE      800000
#define NE2     (2 * NE)
#define NCLS    16

// ---------------- prep: build combined GRU gate matrix ----------------
// Wg[128][64]: rows 0..31  : [Wih_r | Whh_r]   (r gate, K=64 over [a;h])
//              rows 32..63 : [Wih_z | Whh_z]
//              rows 64..95 : [Wih_n | 0    ]   (i_n, K=32 over a)
//              rows 96..127: [0     | Whh_n]   (h_n, K=32 over h)
// bg[128] = [bih_r+bhh_r, bih_z+bhh_z, bih_n, bhh_n]
__global__ __launch_bounds__(256) void prep_kernel(
    const float* __restrict__ Wih, const float* __restrict__ Whh,
    const float* __restrict__ bih, const float* __restrict__ bhh,
    float* __restrict__ Wg, float* __restrict__ bg)
{
    int idx = blockIdx.x * 256 + threadIdx.x;
    if (idx < 8192) {
        int o = idx >> 6, k = idx & 63;
        float val;
        if (o < 64) {
            val = (k < 32) ? Wih[o * 32 + k] : Whh[o * 32 + (k - 32)];
        } else if (o < 96) {
            val = (k < 32) ? Wih[o * 32 + k] : 0.0f;   // Wih rows 64..95 (n)
        } else {
            val = (k >= 32) ? Whh[(o - 32) * 32 + (k - 32)] : 0.0f; // Whh rows 64..95
        }
        Wg[idx] = val;
    } else if (idx < 8320) {
        int i = idx - 8192;
        float val;
        if (i < 64)       val = bih[i] + bhh[i];
        else if (i < 96)  val = bih[i];
        else              val = bhh[i - 32];
        bg[i] = val;
    }
}

// ---------------- u,v projection (shared by init and node kernels) ----------------
__device__ __forceinline__ void proj_uv(const float nn[32], int n,
                                        const float* __restrict__ W1,
                                        float* __restrict__ u, float* __restrict__ v)
{
    for (int j = 0; j < 32; ++j) {          // rolled: W1 addrs uniform per iter -> s_load
        float su = 0.0f, sv = 0.0f;
#pragma unroll
        for (int k = 0; k < 32; ++k) {
            su = fmaf(W1[j * 67 + k],      nn[k], su);
            sv = fmaf(W1[j * 67 + 32 + k], nn[k], sv);
        }
        u[(size_t)n * 32 + j] = su;
        v[(size_t)n * 32 + j] = sv;
    }
}

// ---------------- init: node = classes@W_in.T + b_in; emit u,v; zero acc ----------------
__global__ __launch_bounds__(256) void init_kernel(
    const float* __restrict__ classes, const float* __restrict__ W_in,
    const float* __restrict__ b_in, const float* __restrict__ W1,
    float* __restrict__ node, float* __restrict__ u, float* __restrict__ v,
    float* __restrict__ acc)
{
    int n = blockIdx.x * 256 + threadIdx.x;
    if (n >= NN) return;

    float cls[16];
    const float4* cr = reinterpret_cast<const float4*>(classes + (size_t)n * NCLS);
#pragma unroll
    for (int q = 0; q < 4; ++q) {
        float4 c4 = cr[q];
        cls[q * 4 + 0] = c4.x; cls[q * 4 + 1] = c4.y;
        cls[q * 4 + 2] = c4.z; cls[q * 4 + 3] = c4.w;
    }

    float nn[32];
#pragma unroll
    for (int j = 0; j < 32; ++j) {
        float t = b_in[j];
#pragma unroll
        for (int k = 0; k < 16; ++k) t = fmaf(W_in[j * 16 + k], cls[k], t);
        nn[j] = t;
        node[(size_t)n * 32 + j] = t;
    }

    float4 z4 = make_float4(0.f, 0.f, 0.f, 0.f);
    float4* ar = reinterpret_cast<float4*>(acc + (size_t)n * 32);
#pragma unroll
    for (int q = 0; q < 8; ++q) ar[q] = z4;

    proj_uv(nn, n, W1, u, v);
}

// ---------------- edge kernel: h1 -> h2 -> m -> atomic scatter ----------------
#define H1STEP(j, uu, vv)                                                            \
    {                                                                                \
        float pre = (uu) + (vv) + dx * W1[(j) * 67 + 64] + dy * W1[(j) * 67 + 65]    \
                    + dz * W1[(j) * 67 + 66] + b1[j];                                \
        h1[j] = fmaxf(pre, 0.0f);                                                    \
    }

__global__ __launch_bounds__(256) void edge_kernel(
    const int* __restrict__ e0, const int* __restrict__ e1,
    const float* __restrict__ pos,
    const float* __restrict__ u, const float* __restrict__ v,
    const float* __restrict__ W1, const float* __restrict__ b1,
    const float* __restrict__ W2, const float* __restrict__ b2,
    const float* __restrict__ W3, const float* __restrict__ b3,
    float* __restrict__ acc)
{
    int e = blockIdx.x * 256 + threadIdx.x;   // grid is exactly NE2/256 blocks
    bool rev = e >= NE;
    int ee = rev ? e - NE : e;
    int s = rev ? e1[ee] : e0[ee];
    int d = rev ? e0[ee] : e1[ee];

    float dx = pos[d * 3 + 0] - pos[s * 3 + 0];
    float dy = pos[d * 3 + 1] - pos[s * 3 + 1];
    float dz = pos[d * 3 + 2] - pos[s * 3 + 2];

    const float4* ur = reinterpret_cast<const float4*>(u + (size_t)s * 32);
    const float4* vr = reinterpret_cast<const float4*>(v + (size_t)d * 32);

    float h1[32];
#pragma unroll
    for (int q = 0; q < 8; ++q) {
        float4 uq = ur[q];
        float4 vq = vr[q];
        H1STEP(q * 4 + 0, uq.x, vq.x);
        H1STEP(q * 4 + 1, uq.y, vq.y);
        H1STEP(q * 4 + 2, uq.z, vq.z);
        H1STEP(q * 4 + 3, uq.w, vq.w);
    }

    float h2[32];
#pragma unroll
    for (int o = 0; o < 32; ++o) {
        float t = b2[o];
#pragma unroll
        for (int k = 0; k < 32; ++k) t = fmaf(W2[o * 32 + k], h1[k], t);
        h2[o] = fmaxf(t, 0.0f);
    }

    float* arow = acc + (size_t)s * 32;
#pragma unroll
    for (int o = 0; o < 32; ++o) {
        float t = b3[o];
#pragma unroll
        for (int k = 0; k < 32; ++k) t = fmaf(W3[o * 32 + k], h2[k], t);
        unsafeAtomicAdd(arow + o, t);   // native global_atomic_add_f32
    }
}

// ---------------- node kernel: GRU update + next-iter u,v; re-zero acc ----------------
__global__ __launch_bounds__(256) void node_kernel(
    float* __restrict__ node, float* __restrict__ acc,
    const float* __restrict__ Wg, const float* __restrict__ bg,
    const float* __restrict__ W1,
    float* __restrict__ u, float* __restrict__ v, int last)
{
    __shared__ float nn_lds[32][256];   // lane-private column scratch (no barriers)
    int n = blockIdx.x * 256 + threadIdx.x;
    if (n >= NN) return;
    int tid = threadIdx.x;

    float a[32], h[32];
    const float4* ar = reinterpret_cast<const float4*>(acc + (size_t)n * 32);
    const float4* hr = reinterpret_cast<const float4*>(node + (size_t)n * 32);
#pragma unroll
    for (int q = 0; q < 8; ++q) {
        float4 a4 = ar[q];
        a[q * 4 + 0] = a4.x; a[q * 4 + 1] = a4.y; a[q * 4 + 2] = a4.z; a[q * 4 + 3] = a4.w;
        float4 h4 = hr[q];
        h[q * 4 + 0] = h4.x; h[q * 4 + 1] = h4.y; h[q * 4 + 2] = h4.z; h[q * 4 + 3] = h4.w;
    }

    // re-zero acc row for the next edge pass
    float4 z4 = make_float4(0.f, 0.f, 0.f, 0.f);
    float4* aw = reinterpret_cast<float4*>(acc + (size_t)n * 32);
#pragma unroll
    for (int q = 0; q < 8; ++q) aw[q] = z4;

    for (int j = 0; j < 32; ++j) {   // rolled: Wg addrs uniform per iter -> s_load
        float gr = bg[j], gz = bg[32 + j], gin = bg[64 + j], ghn = bg[96 + j];
#pragma unroll
        for (int k = 0; k < 32; ++k) {
            gr  = fmaf(Wg[j * 64 + k],             a[k], gr);
            gr  = fmaf(Wg[j * 64 + 32 + k],        h[k], gr);
            gz  = fmaf(Wg[(32 + j) * 64 + k],      a[k], gz);
            gz  = fmaf(Wg[(32 + j) * 64 + 32 + k], h[k], gz);
            gin = fmaf(Wg[(64 + j) * 64 + k],      a[k], gin);
            ghn = fmaf(Wg[(96 + j) * 64 + 32 + k], h[k], ghn);
        }
        float r  = 1.0f / (1.0f + expf(-gr));
        float zz = 1.0f / (1.0f + expf(-gz));
        float nj = tanhf(fmaf(r, ghn, gin));
        float out = fmaf(zz, h[j] - nj, nj);      // (1-z)*n + z*h
        node[(size_t)n * 32 + j] = out;
        nn_lds[j][tid] = out;
    }

    if (!last) {
        float nn[32];
#pragma unroll
        for (int k = 0; k < 32; ++k) nn[k] = nn_lds[k][tid];
        proj_uv(nn, n, W1, u, v);
    }
}

// ---------------- launch ----------------
extern "C" void kernel_launch(void* const* d_in, const int* in_sizes, int n_in,
                              void* d_out, int out_size, void* d_ws, size_t ws_size,
                              hipStream_t stream)
{
    const float* pos     = (const float*)d_in[0];
    const float* classes = (const float*)d_in[1];
    const int*   edges   = (const int*)d_in[2];
    // d_in[3] = n_graphs (unused: equal-size reshape is identity on flat memory)
    const float* W_in = (const float*)d_in[4];
    const float* b_in = (const float*)d_in[5];
    const float* W1   = (const float*)d_in[6];
    const float* b1   = (const float*)d_in[7];
    const float* W2   = (const float*)d_in[8];
    const float* b2   = (const float*)d_in[9];
    const float* W3   = (const float*)d_in[10];
    const float* b3   = (const float*)d_in[11];
    const float* Wih_n = (const float*)d_in[12];
    const float* Whh_n = (const float*)d_in[13];
    const float* bih_n = (const float*)d_in[14];
    const float* bhh_n = (const float*)d_in[15];
    // d_in[16..19]: edge-GRU params — dead w.r.t. the output.

    float* node = (float*)d_out;                 // [50000][32], persistent node state
    float* ws   = (float*)d_ws;
    float* u   = ws;                              // [50000][32]
    float* v   = u + (size_t)NN * 32;             // [50000][32]
    float* acc = v + (size_t)NN * 32;             // [50000][32]
    float* Wg  = acc + (size_t)NN * 32;           // [128][64]
    float* bg  = Wg + 128 * 64;                   // [128]

    const int* e0 = edges;
    const int* e1 = edges + NE;

    prep_kernel<<<33, 256, 0, stream>>>(Wih_n, Whh_n, bih_n, bhh_n, Wg, bg);
    init_kernel<<<(NN + 255) / 256, 256, 0, stream>>>(classes, W_in, b_in, W1,
                                                      node, u, v, acc);
    for (int it = 0; it < 6; ++it) {
        edge_kernel<<<NE2 / 256, 256, 0, stream>>>(e0, e1, pos, u, v,
                                                   W1, b1, W2, b2, W3, b3, acc);
        node_kernel<<<(NN + 255) / 256, 256, 0, stream>>>(node, acc, Wg, bg, W1,
                                                          u, v, it == 5);
    }
}

// Round 2
// 2084.963 us; speedup vs baseline: 7.8208x; 7.8208x over previous
//
#include <hip/hip_runtime.h>

// MPNN encoder, MI355X — round 2.
// Round-1 rocprof: edge_kernel VALUBusy 3.6%, WRITE_SIZE 1.6 GB/dispatch
// (= 51.2M scattered f32 atomics x 32B write-through). Atomic scatter was the
// bottleneck, not compute. Fix: counting-sort directed edges by source once
// per launch; edge kernel writes messages coalesced; CSR gather sums them.
//
//  - edge_feat / GRU_e dead w.r.t. output -> skipped.
//  - layer1 factorized: h1 = relu(u[s] + v[d] + W1p*dpos + b1).
//  - segment_sum via sort + coalesced materialize + CSR gather (no atomics).

#define NN      50000
#define NE      800000
#define NE2     (2 * NE)
#define NCLS    16

// ---------------- prep: build combined GRU gate matrix ----------------
__global__ __launch_bounds__(256) void prep_kernel(
    const float* __restrict__ Wih, const float* __restrict__ Whh,
    const float* __restrict__ bih, const float* __restrict__ bhh,
    float* __restrict__ Wg, float* __restrict__ bg)
{
    int idx = blockIdx.x * 256 + threadIdx.x;
    if (idx < 8192) {
        int o = idx >> 6, k = idx & 63;
        float val;
        if (o < 64) {
            val = (k < 32) ? Wih[o * 32 + k] : Whh[o * 32 + (k - 32)];
        } else if (o < 96) {
            val = (k < 32) ? Wih[o * 32 + k] : 0.0f;
        } else {
            val = (k >= 32) ? Whh[(o - 32) * 32 + (k - 32)] : 0.0f;
        }
        Wg[idx] = val;
    } else if (idx < 8320) {
        int i = idx - 8192;
        float val;
        if (i < 64)       val = bih[i] + bhh[i];
        else if (i < 96)  val = bih[i];
        else              val = bhh[i - 32];
        bg[i] = val;
    }
}

// ---------------- sorting: histogram, scan, scatter ----------------
__global__ __launch_bounds__(256) void zero_deg_kernel(int* __restrict__ deg)
{
    int i = blockIdx.x * 256 + threadIdx.x;
    if (i < NN) deg[i] = 0;
}

__global__ __launch_bounds__(256) void hist_kernel(
    const int* __restrict__ e0, const int* __restrict__ e1, int* __restrict__ deg)
{
    int e = blockIdx.x * 256 + threadIdx.x;   // grid exactly NE2/256
    int s = (e < NE) ? e0[e] : e1[e - NE];
    atomicAdd(&deg[s], 1);
}

__global__ __launch_bounds__(1024) void scan_kernel(
    const int* __restrict__ deg, int* __restrict__ rowptr, int* __restrict__ cursor)
{
    __shared__ int sdata[1024];
    __shared__ int carry_s;
    int tid = threadIdx.x;
    if (tid == 0) carry_s = 0;
    __syncthreads();
    for (int base = 0; base < NN; base += 1024) {
        int i = base + tid;
        int x = (i < NN) ? deg[i] : 0;
        sdata[tid] = x;
        __syncthreads();
        for (int off = 1; off < 1024; off <<= 1) {
            int t = (tid >= off) ? sdata[tid - off] : 0;
            __syncthreads();
            sdata[tid] += t;
            __syncthreads();
        }
        int incl = sdata[tid];
        int excl = incl - x;
        int carry = carry_s;
        if (i < NN) { rowptr[i] = carry + excl; cursor[i] = carry + excl; }
        __syncthreads();
        if (tid == 1023) carry_s = carry + incl;
        __syncthreads();
    }
    if (tid == 0) rowptr[NN] = carry_s;   // == NE2
}

__global__ __launch_bounds__(256) void scatter_kernel(
    const int* __restrict__ e0, const int* __restrict__ e1,
    int* __restrict__ cursor, int* __restrict__ ssorted, int* __restrict__ dsorted)
{
    int e = blockIdx.x * 256 + threadIdx.x;   // grid exactly NE2/256
    int s, d;
    if (e < NE) { s = e0[e]; d = e1[e]; }
    else        { s = e1[e - NE]; d = e0[e - NE]; }
    int p = atomicAdd(&cursor[s], 1);
    ssorted[p] = s;
    dsorted[p] = d;
}

// ---------------- u,v projection ----------------
__device__ __forceinline__ void proj_uv(const float nn[32], int n,
                                        const float* __restrict__ W1,
                                        float* __restrict__ u, float* __restrict__ v)
{
    for (int j = 0; j < 32; ++j) {          // rolled: W1 addrs uniform -> s_load
        float su = 0.0f, sv = 0.0f;
#pragma unroll
        for (int k = 0; k < 32; ++k) {
            su = fmaf(W1[j * 67 + k],      nn[k], su);
            sv = fmaf(W1[j * 67 + 32 + k], nn[k], sv);
        }
        u[(size_t)n * 32 + j] = su;
        v[(size_t)n * 32 + j] = sv;
    }
}

// ---------------- init: node = classes@W_in.T + b_in; emit u,v ----------------
__global__ __launch_bounds__(256) void init_kernel(
    const float* __restrict__ classes, const float* __restrict__ W_in,
    const float* __restrict__ b_in, const float* __restrict__ W1,
    float* __restrict__ node, float* __restrict__ u, float* __restrict__ v)
{
    int n = blockIdx.x * 256 + threadIdx.x;
    if (n >= NN) return;

    float cls[16];
    const float4* cr = reinterpret_cast<const float4*>(classes + (size_t)n * NCLS);
#pragma unroll
    for (int q = 0; q < 4; ++q) {
        float4 c4 = cr[q];
        cls[q * 4 + 0] = c4.x; cls[q * 4 + 1] = c4.y;
        cls[q * 4 + 2] = c4.z; cls[q * 4 + 3] = c4.w;
    }

    float nn[32];
#pragma unroll
    for (int j = 0; j < 32; ++j) {
        float t = b_in[j];
#pragma unroll
        for (int k = 0; k < 16; ++k) t = fmaf(W_in[j * 16 + k], cls[k], t);
        nn[j] = t;
        node[(size_t)n * 32 + j] = t;
    }

    proj_uv(nn, n, W1, u, v);
}

// ---------------- edge kernel: h1 -> h2 -> m, coalesced store ----------------
#define H1STEP(j, uu, vv)                                                            \
    {                                                                                \
        float pre = (uu) + (vv) + dx * W1[(j) * 67 + 64] + dy * W1[(j) * 67 + 65]    \
                    + dz * W1[(j) * 67 + 66] + b1[j];                                \
        h1[j] = fmaxf(pre, 0.0f);                                                    \
    }

__global__ __launch_bounds__(256) void edge_kernel(
    const int* __restrict__ ssorted, const int* __restrict__ dsorted,
    const float* __restrict__ pos,
    const float* __restrict__ u, const float* __restrict__ v,
    const float* __restrict__ W1, const float* __restrict__ b1,
    const float* __restrict__ W2, const float* __restrict__ b2,
    const float* __restrict__ W3, const float* __restrict__ b3,
    float* __restrict__ mbuf)
{
    int e = blockIdx.x * 256 + threadIdx.x;   // grid exactly NE2/256
    int s = ssorted[e];                        // sorted: near wave-uniform
    int d = dsorted[e];

    float dx = pos[d * 3 + 0] - pos[s * 3 + 0];
    float dy = pos[d * 3 + 1] - pos[s * 3 + 1];
    float dz = pos[d * 3 + 2] - pos[s * 3 + 2];

    const float4* ur = reinterpret_cast<const float4*>(u + (size_t)s * 32);
    const float4* vr = reinterpret_cast<const float4*>(v + (size_t)d * 32);

    float h1[32];
#pragma unroll
    for (int q = 0; q < 8; ++q) {
        float4 uq = ur[q];
        float4 vq = vr[q];
        H1STEP(q * 4 + 0, uq.x, vq.x);
        H1STEP(q * 4 + 1, uq.y, vq.y);
        H1STEP(q * 4 + 2, uq.z, vq.z);
        H1STEP(q * 4 + 3, uq.w, vq.w);
    }

    float h2[32];
#pragma unroll
    for (int o = 0; o < 32; ++o) {
        float t = b2[o];
#pragma unroll
        for (int k = 0; k < 32; ++k) t = fmaf(W2[o * 32 + k], h1[k], t);
        h2[o] = fmaxf(t, 0.0f);
    }

    float4* mw = reinterpret_cast<float4*>(mbuf + (size_t)e * 32);
#pragma unroll
    for (int q = 0; q < 8; ++q) {
        float4 m4;
        float* mm = &m4.x;
#pragma unroll
        for (int jj = 0; jj < 4; ++jj) {
            int o = q * 4 + jj;
            float t = b3[o];
#pragma unroll
            for (int k = 0; k < 32; ++k) t = fmaf(W3[o * 32 + k], h2[k], t);
            mm[jj] = t;
        }
        mw[q] = m4;
    }
}

// ---------------- gather: one wave per node, sum contiguous m rows ----------------
__global__ __launch_bounds__(256) void gather_kernel(
    const float* __restrict__ mbuf, const int* __restrict__ rowptr,
    float* __restrict__ acc)
{
    int wid = (blockIdx.x * 256 + threadIdx.x) >> 6;   // global wave id = node
    if (wid >= NN) return;
    int lane = threadIdx.x & 63;
    int r = lane >> 5, c = lane & 31;
    int beg = rowptr[wid], end = rowptr[wid + 1];
    float sum = 0.0f;
    for (int i = beg + r; i < end; i += 2)
        sum += mbuf[(size_t)i * 32 + c];               // 256B/wave, coalesced
    sum += __shfl_xor(sum, 32);
    if (r == 0) acc[(size_t)wid * 32 + c] = sum;
}

// ---------------- node kernel: GRU update + next-iter u,v ----------------
__global__ __launch_bounds__(256) void node_kernel(
    float* __restrict__ node, const float* __restrict__ acc,
    const float* __restrict__ Wg, const float* __restrict__ bg,
    const float* __restrict__ W1,
    float* __restrict__ u, float* __restrict__ v, int last)
{
    __shared__ float nn_lds[32][256];   // lane-private column scratch (no barriers)
    int n = blockIdx.x * 256 + threadIdx.x;
    if (n >= NN) return;
    int tid = threadIdx.x;

    float a[32], h[32];
    const float4* ar = reinterpret_cast<const float4*>(acc + (size_t)n * 32);
    const float4* hr = reinterpret_cast<const float4*>(node + (size_t)n * 32);
#pragma unroll
    for (int q = 0; q < 8; ++q) {
        float4 a4 = ar[q];
        a[q * 4 + 0] = a4.x; a[q * 4 + 1] = a4.y; a[q * 4 + 2] = a4.z; a[q * 4 + 3] = a4.w;
        float4 h4 = hr[q];
        h[q * 4 + 0] = h4.x; h[q * 4 + 1] = h4.y; h[q * 4 + 2] = h4.z; h[q * 4 + 3] = h4.w;
    }

    for (int j = 0; j < 32; ++j) {   // rolled: Wg addrs uniform -> s_load
        float gr = bg[j], gz = bg[32 + j], gin = bg[64 + j], ghn = bg[96 + j];
#pragma unroll
        for (int k = 0; k < 32; ++k) {
            gr  = fmaf(Wg[j * 64 + k],             a[k], gr);
            gr  = fmaf(Wg[j * 64 + 32 + k],        h[k], gr);
            gz  = fmaf(Wg[(32 + j) * 64 + k],      a[k], gz);
            gz  = fmaf(Wg[(32 + j) * 64 + 32 + k], h[k], gz);
            gin = fmaf(Wg[(64 + j) * 64 + k],      a[k], gin);
            ghn = fmaf(Wg[(96 + j) * 64 + 32 + k], h[k], ghn);
        }
        float r  = 1.0f / (1.0f + expf(-gr));
        float zz = 1.0f / (1.0f + expf(-gz));
        float nj = tanhf(fmaf(r, ghn, gin));
        float out = fmaf(zz, h[j] - nj, nj);      // (1-z)*n + z*h
        node[(size_t)n * 32 + j] = out;
        nn_lds[j][tid] = out;
    }

    if (!last) {
        float nn[32];
#pragma unroll
        for (int k = 0; k < 32; ++k) nn[k] = nn_lds[k][tid];
        proj_uv(nn, n, W1, u, v);
    }
}

// ---------------- launch ----------------
extern "C" void kernel_launch(void* const* d_in, const int* in_sizes, int n_in,
                              void* d_out, int out_size, void* d_ws, size_t ws_size,
                              hipStream_t stream)
{
    const float* pos     = (const float*)d_in[0];
    const float* classes = (const float*)d_in[1];
    const int*   edges   = (const int*)d_in[2];
    const float* W_in = (const float*)d_in[4];
    const float* b_in = (const float*)d_in[5];
    const float* W1   = (const float*)d_in[6];
    const float* b1   = (const float*)d_in[7];
    const float* W2   = (const float*)d_in[8];
    const float* b2   = (const float*)d_in[9];
    const float* W3   = (const float*)d_in[10];
    const float* b3   = (const float*)d_in[11];
    const float* Wih_n = (const float*)d_in[12];
    const float* Whh_n = (const float*)d_in[13];
    const float* bih_n = (const float*)d_in[14];
    const float* bhh_n = (const float*)d_in[15];
    // d_in[16..19]: edge-GRU params — dead w.r.t. the output.

    float* node = (float*)d_out;                  // [NN][32] persistent

    float* ws  = (float*)d_ws;
    float* u   = ws;                              // [NN][32]
    float* v   = u + (size_t)NN * 32;             // [NN][32]
    float* acc = v + (size_t)NN * 32;             // [NN][32]
    float* Wg  = acc + (size_t)NN * 32;           // [128][64]
    float* bg  = Wg + 128 * 64;                   // [128]
    int* deg     = (int*)(bg + 128);              // [NN]
    int* cursor  = deg + NN;                      // [NN]
    int* rowptr  = cursor + NN;                   // [NN+1]
    int* ssorted = rowptr + (NN + 1);             // [NE2]
    int* dsorted = ssorted + NE2;                 // [NE2]
    uintptr_t mp = (uintptr_t)(dsorted + NE2);
    mp = (mp + 255) & ~(uintptr_t)255;
    float* mbuf = (float*)mp;                     // [NE2][32] ~ 204.8 MB

    const int* e0 = edges;
    const int* e1 = edges + NE;

    prep_kernel<<<33, 256, 0, stream>>>(Wih_n, Whh_n, bih_n, bhh_n, Wg, bg);
    zero_deg_kernel<<<(NN + 255) / 256, 256, 0, stream>>>(deg);
    hist_kernel<<<NE2 / 256, 256, 0, stream>>>(e0, e1, deg);
    scan_kernel<<<1, 1024, 0, stream>>>(deg, rowptr, cursor);
    scatter_kernel<<<NE2 / 256, 256, 0, stream>>>(e0, e1, cursor, ssorted, dsorted);
    init_kernel<<<(NN + 255) / 256, 256, 0, stream>>>(classes, W_in, b_in, W1,
                                                      node, u, v);
    for (int it = 0; it < 6; ++it) {
        edge_kernel<<<NE2 / 256, 256, 0, stream>>>(ssorted, dsorted, pos, u, v,
                                                   W1, b1, W2, b2, W3, b3, mbuf);
        gather_kernel<<<(NN * 64 + 255) / 256, 256, 0, stream>>>(mbuf, rowptr, acc);
        node_kernel<<<(NN + 255) / 256, 256, 0, stream>>>(node, acc, Wg, bg, W1,
                                                          u, v, it == 5);
    }
}

// Round 3
// 1471.860 us; speedup vs baseline: 11.0786x; 1.4165x over previous
//
#include <hip/hip_runtime.h>

// MPNN encoder, MI355X — round 3.
// Round-2 rocprof: edge_kernel WRITE_SIZE 445MB (2.2x amplified mbuf) + gather
// re-read 205MB per iter = avoidable traffic; scatter's atomic->scattered-write
// chain pathological under profiling. Fix: fuse segmented reduction into the
// edge kernel via LDS (no mbuf, no gather kernel); boundary-only f32 atomics
// (~3.2M/iter vs 51.2M round-1); rank-based race-free counting sort.
//
//  - edge_feat / GRU_e dead w.r.t. output -> skipped.
//  - layer1 factorized: h1 = relu(u[s] + v[d] + W1p*dpos + b1).

#define NN      50000
#define NE      800000
#define NE2     (2 * NE)
#define NCLS    16

// ---------------- prep: build combined GRU gate matrix ----------------
__global__ __launch_bounds__(256) void prep_kernel(
    const float* __restrict__ Wih, const float* __restrict__ Whh,
    const float* __restrict__ bih, const float* __restrict__ bhh,
    float* __restrict__ Wg, float* __restrict__ bg)
{
    int idx = blockIdx.x * 256 + threadIdx.x;
    if (idx < 8192) {
        int o = idx >> 6, k = idx & 63;
        float val;
        if (o < 64) {
            val = (k < 32) ? Wih[o * 32 + k] : Whh[o * 32 + (k - 32)];
        } else if (o < 96) {
            val = (k < 32) ? Wih[o * 32 + k] : 0.0f;
        } else {
            val = (k >= 32) ? Whh[(o - 32) * 32 + (k - 32)] : 0.0f;
        }
        Wg[idx] = val;
    } else if (idx < 8320) {
        int i = idx - 8192;
        float val;
        if (i < 64)       val = bih[i] + bhh[i];
        else if (i < 96)  val = bih[i];
        else              val = bhh[i - 32];
        bg[i] = val;
    }
}

// ---------------- sort: rank-histogram, scan, scatter ----------------
__global__ __launch_bounds__(256) void zero_deg_kernel(int* __restrict__ deg)
{
    int i = blockIdx.x * 256 + threadIdx.x;
    if (i < NN) deg[i] = 0;
}

__global__ __launch_bounds__(256) void hist_rank_kernel(
    const int* __restrict__ e0, const int* __restrict__ e1,
    int* __restrict__ deg, int* __restrict__ rank)
{
    int e = blockIdx.x * 256 + threadIdx.x;   // grid exactly NE2/256
    int s = (e < NE) ? e0[e] : e1[e - NE];
    rank[e] = atomicAdd(&deg[s], 1);          // rank store is coalesced
}

// 1024 threads; each scans 49 contiguous elements serially; block-scan of partials.
__global__ __launch_bounds__(1024) void scan_kernel(
    const int* __restrict__ deg, int* __restrict__ rowptr)
{
    __shared__ int part[1024];
    int tid = threadIdx.x;
    int beg = tid * 49;                        // 1024*49 = 50176 >= NN
    int sum = 0;
#pragma unroll 7
    for (int i = 0; i < 49; ++i) {
        int idx = beg + i;
        if (idx < NN) sum += deg[idx];
    }
    part[tid] = sum;
    __syncthreads();
    for (int off = 1; off < 1024; off <<= 1) {
        int t = (tid >= off) ? part[tid - off] : 0;
        __syncthreads();
        part[tid] += t;
        __syncthreads();
    }
    int run = part[tid] - sum;                 // exclusive prefix
#pragma unroll 7
    for (int i = 0; i < 49; ++i) {
        int idx = beg + i;
        if (idx < NN) { rowptr[idx] = run; run += deg[idx]; }
    }
    if (tid == 1023) rowptr[NN] = run;         // == NE2
}

__global__ __launch_bounds__(256) void scatter_kernel(
    const int* __restrict__ e0, const int* __restrict__ e1,
    const int* __restrict__ rowptr, const int* __restrict__ rank,
    int2* __restrict__ sd)
{
    int e = blockIdx.x * 256 + threadIdx.x;   // grid exactly NE2/256
    int s, d;
    if (e < NE) { s = e0[e]; d = e1[e]; }
    else        { s = e1[e - NE]; d = e0[e - NE]; }
    int p = rowptr[s] + rank[e];
    sd[p] = make_int2(s, d);                  // single scattered 8B store
}

// ---------------- u,v projection ----------------
__device__ __forceinline__ void proj_uv(const float nn[32], int n,
                                        const float* __restrict__ W1,
                                        float* __restrict__ u, float* __restrict__ v)
{
    for (int j = 0; j < 32; ++j) {            // rolled: W1 addrs uniform -> s_load
        float su = 0.0f, sv = 0.0f;
#pragma unroll
        for (int k = 0; k < 32; ++k) {
            su = fmaf(W1[j * 67 + k],      nn[k], su);
            sv = fmaf(W1[j * 67 + 32 + k], nn[k], sv);
        }
        u[(size_t)n * 32 + j] = su;
        v[(size_t)n * 32 + j] = sv;
    }
}

// ---------------- init: node = classes@W_in.T + b_in; emit u,v; zero acc ------
__global__ __launch_bounds__(256) void init_kernel(
    const float* __restrict__ classes, const float* __restrict__ W_in,
    const float* __restrict__ b_in, const float* __restrict__ W1,
    float* __restrict__ node, float* __restrict__ u, float* __restrict__ v,
    float* __restrict__ acc)
{
    int n = blockIdx.x * 256 + threadIdx.x;
    if (n >= NN) return;

    float cls[16];
    const float4* cr = reinterpret_cast<const float4*>(classes + (size_t)n * NCLS);
#pragma unroll
    for (int q = 0; q < 4; ++q) {
        float4 c4 = cr[q];
        cls[q * 4 + 0] = c4.x; cls[q * 4 + 1] = c4.y;
        cls[q * 4 + 2] = c4.z; cls[q * 4 + 3] = c4.w;
    }

    float nn[32];
#pragma unroll
    for (int j = 0; j < 32; ++j) {
        float t = b_in[j];
#pragma unroll
        for (int k = 0; k < 16; ++k) t = fmaf(W_in[j * 16 + k], cls[k], t);
        nn[j] = t;
        node[(size_t)n * 32 + j] = t;
    }

    float4 z4 = make_float4(0.f, 0.f, 0.f, 0.f);
    float4* aw = reinterpret_cast<float4*>(acc + (size_t)n * 32);
#pragma unroll
    for (int q = 0; q < 8; ++q) aw[q] = z4;

    proj_uv(nn, n, W1, u, v);
}

// ---------------- fused edge kernel: MLP -> LDS -> segmented reduce ----------
#define H1STEP(j, uu, vv)                                                            \
    {                                                                                \
        float pre = (uu) + (vv) + dx * W1[(j) * 67 + 64] + dy * W1[(j) * 67 + 65]    \
                    + dz * W1[(j) * 67 + 66] + b1[j];                                \
        h1[j] = fmaxf(pre, 0.0f);                                                    \
    }

__global__ __launch_bounds__(256) void edge_kernel(
    const int2* __restrict__ sd, const float* __restrict__ pos,
    const float* __restrict__ u, const float* __restrict__ v,
    const float* __restrict__ W1, const float* __restrict__ b1,
    const float* __restrict__ W2, const float* __restrict__ b2,
    const float* __restrict__ W3, const float* __restrict__ b3,
    float* __restrict__ acc)
{
    // row stride 36 floats = 144B: ds_write_b128 hits the 8-cycle floor
    // (16B bank-groups cycle evenly); scalar column reads conflict-free.
    __shared__ float mld[256][36];
    __shared__ int   slds[256];

    int tid = threadIdx.x;
    int e = blockIdx.x * 256 + tid;           // grid exactly NE2/256
    int2 p = sd[e];
    int s = p.x, d = p.y;
    slds[tid] = s;

    float dx = pos[d * 3 + 0] - pos[s * 3 + 0];
    float dy = pos[d * 3 + 1] - pos[s * 3 + 1];
    float dz = pos[d * 3 + 2] - pos[s * 3 + 2];

    const float4* ur = reinterpret_cast<const float4*>(u + (size_t)s * 32);
    const float4* vr = reinterpret_cast<const float4*>(v + (size_t)d * 32);

    float h1[32];
#pragma unroll
    for (int q = 0; q < 8; ++q) {
        float4 uq = ur[q];
        float4 vq = vr[q];
        H1STEP(q * 4 + 0, uq.x, vq.x);
        H1STEP(q * 4 + 1, uq.y, vq.y);
        H1STEP(q * 4 + 2, uq.z, vq.z);
        H1STEP(q * 4 + 3, uq.w, vq.w);
    }

    float h2[32];
#pragma unroll
    for (int o = 0; o < 32; ++o) {
        float t = b2[o];
#pragma unroll
        for (int k = 0; k < 32; ++k) t = fmaf(W2[o * 32 + k], h1[k], t);
        h2[o] = fmaxf(t, 0.0f);
    }

#pragma unroll
    for (int q = 0; q < 8; ++q) {
        float4 m4;
        float* mm = &m4.x;
#pragma unroll
        for (int jj = 0; jj < 4; ++jj) {
            int o = q * 4 + jj;
            float t = b3[o];
#pragma unroll
            for (int k = 0; k < 32; ++k) t = fmaf(W3[o * 32 + k], h2[k], t);
            mm[jj] = t;
        }
        *reinterpret_cast<float4*>(&mld[tid][q * 4]) = m4;
    }
    __syncthreads();

    // segmented reduce: thread (c, j) sums a 32-row window of column c;
    // sources are sorted, so breaks are rare (~2 per window).
    int c = tid & 31, j = tid >> 5;
    int base = j * 32;
    int scur = slds[base];
    float sum = 0.0f;
    for (int r = 0; r < 32; ++r) {
        int row = base + r;
        int sr = slds[row];                    // half-wave-uniform branch
        if (sr != scur) {
            unsafeAtomicAdd(&acc[(size_t)scur * 32 + c], sum);
            sum = 0.0f;
            scur = sr;
        }
        sum += mld[row][c];
    }
    unsafeAtomicAdd(&acc[(size_t)scur * 32 + c], sum);
}

// ---------------- node kernel: GRU update + next-iter u,v; re-zero acc -------
__global__ __launch_bounds__(256) void node_kernel(
    float* __restrict__ node, float* __restrict__ acc,
    const float* __restrict__ Wg, const float* __restrict__ bg,
    const float* __restrict__ W1,
    float* __restrict__ u, float* __restrict__ v, int last)
{
    __shared__ float nn_lds[32][256];   // lane-private column scratch (no barriers)
    int n = blockIdx.x * 256 + threadIdx.x;
    if (n >= NN) return;
    int tid = threadIdx.x;

    float a[32], h[32];
    const float4* ar = reinterpret_cast<const float4*>(acc + (size_t)n * 32);
    const float4* hr = reinterpret_cast<const float4*>(node + (size_t)n * 32);
#pragma unroll
    for (int q = 0; q < 8; ++q) {
        float4 a4 = ar[q];
        a[q * 4 + 0] = a4.x; a[q * 4 + 1] = a4.y; a[q * 4 + 2] = a4.z; a[q * 4 + 3] = a4.w;
        float4 h4 = hr[q];
        h[q * 4 + 0] = h4.x; h[q * 4 + 1] = h4.y; h[q * 4 + 2] = h4.z; h[q * 4 + 3] = h4.w;
    }

    // re-zero acc row for the next edge pass
    float4 z4 = make_float4(0.f, 0.f, 0.f, 0.f);
    float4* aw = reinterpret_cast<float4*>(acc + (size_t)n * 32);
#pragma unroll
    for (int q = 0; q < 8; ++q) aw[q] = z4;

    for (int j = 0; j < 32; ++j) {   // rolled: Wg addrs uniform -> s_load
        float gr = bg[j], gz = bg[32 + j], gin = bg[64 + j], ghn = bg[96 + j];
#pragma unroll
        for (int k = 0; k < 32; ++k) {
            gr  = fmaf(Wg[j * 64 + k],             a[k], gr);
            gr  = fmaf(Wg[j * 64 + 32 + k],        h[k], gr);
            gz  = fmaf(Wg[(32 + j) * 64 + k],      a[k], gz);
            gz  = fmaf(Wg[(32 + j) * 64 + 32 + k], h[k], gz);
            gin = fmaf(Wg[(64 + j) * 64 + k],      a[k], gin);
            ghn = fmaf(Wg[(96 + j) * 64 + 32 + k], h[k], ghn);
        }
        float r  = 1.0f / (1.0f + expf(-gr));
        float zz = 1.0f / (1.0f + expf(-gz));
        float nj = tanhf(fmaf(r, ghn, gin));
        float out = fmaf(zz, h[j] - nj, nj);      // (1-z)*n + z*h
        node[(size_t)n * 32 + j] = out;
        nn_lds[j][tid] = out;
    }

    if (!last) {
        float nn[32];
#pragma unroll
        for (int k = 0; k < 32; ++k) nn[k] = nn_lds[k][tid];
        proj_uv(nn, n, W1, u, v);
    }
}

// ---------------- launch ----------------
extern "C" void kernel_launch(void* const* d_in, const int* in_sizes, int n_in,
                              void* d_out, int out_size, void* d_ws, size_t ws_size,
                              hipStream_t stream)
{
    const float* pos     = (const float*)d_in[0];
    const float* classes = (const float*)d_in[1];
    const int*   edges   = (const int*)d_in[2];
    const float* W_in = (const float*)d_in[4];
    const float* b_in = (const float*)d_in[5];
    const float* W1   = (const float*)d_in[6];
    const float* b1   = (const float*)d_in[7];
    const float* W2   = (const float*)d_in[8];
    const float* b2   = (const float*)d_in[9];
    const float* W3   = (const float*)d_in[10];
    const float* b3   = (const float*)d_in[11];
    const float* Wih_n = (const float*)d_in[12];
    const float* Whh_n = (const float*)d_in[13];
    const float* bih_n = (const float*)d_in[14];
    const float* bhh_n = (const float*)d_in[15];
    // d_in[16..19]: edge-GRU params — dead w.r.t. the output.

    float* node = (float*)d_out;                  // [NN][32] persistent

    float* ws  = (float*)d_ws;
    float* u   = ws;                              // [NN][32]
    float* v   = u + (size_t)NN * 32;             // [NN][32]
    float* acc = v + (size_t)NN * 32;             // [NN][32]
    float* Wg  = acc + (size_t)NN * 32;           // [128][64]
    float* bg  = Wg + 128 * 64;                   // [128]
    int* deg    = (int*)(bg + 128);               // [NN]
    int* rank   = deg + NN;                       // [NE2]
    int* rowptr = rank + NE2;                     // [NN+1]
    uintptr_t sp = (uintptr_t)(rowptr + NN + 1);
    sp = (sp + 255) & ~(uintptr_t)255;
    int2* sd = (int2*)sp;                         // [NE2] packed (s,d)

    const int* e0 = edges;
    const int* e1 = edges + NE;

    prep_kernel<<<33, 256, 0, stream>>>(Wih_n, Whh_n, bih_n, bhh_n, Wg, bg);
    zero_deg_kernel<<<(NN + 255) / 256, 256, 0, stream>>>(deg);
    hist_rank_kernel<<<NE2 / 256, 256, 0, stream>>>(e0, e1, deg, rank);
    scan_kernel<<<1, 1024, 0, stream>>>(deg, rowptr);
    scatter_kernel<<<NE2 / 256, 256, 0, stream>>>(e0, e1, rowptr, rank, sd);
    init_kernel<<<(NN + 255) / 256, 256, 0, stream>>>(classes, W_in, b_in, W1,
                                                      node, u, v, acc);
    for (int it = 0; it < 6; ++it) {
        edge_kernel<<<NE2 / 256, 256, 0, stream>>>(sd, pos, u, v,
                                                   W1, b1, W2, b2, W3, b3, acc);
        node_kernel<<<(NN + 255) / 256, 256, 0, stream>>>(node, acc, Wg, bg, W1,
                                                          u, v, it == 5);
    }
}